// Round 2
// baseline (6120.038 us; speedup 1.0000x reference)
//
#include <hip/hip_runtime.h>
#include <math.h>

#define B_ 32
#define T_ 512
#define I_ 512
#define H_ 1024
#define O_ 512
#define MT (B_*T_)   // 16384 rows

// Barrier counters for the cooperative RNN kernel: 8 groups x 32 uints.
// Device global (not d_ws: workspace may be zero-sized). Zeroed by phase-1
// GEMM block (0,0) so every graph replay starts from a clean state.
__device__ unsigned g_cnt[256];

// ---------------------------------------------------------------------------
// GEMM: C[m][n] = bias[n] + sum_k A[m][k] * Bm[n][k]   (both row-major, "NT")
// BM=BN=128, BK=16, 256 threads, 8x8 microtile per thread.
// ---------------------------------------------------------------------------
__global__ __launch_bounds__(256)
void gemm_nt_bias(float* __restrict__ C, const float* __restrict__ A,
                  const float* __restrict__ Bm, const float* __restrict__ bias,
                  int M, int N, int K, unsigned* __restrict__ cnt) {
  __shared__ float As[16][132];   // [k][m], +4 pad keeps 16B align, breaks stride
  __shared__ float Bs[16][132];   // [k][n]
  const int tid = threadIdx.x;
  if (cnt != nullptr && blockIdx.x == 0 && blockIdx.y == 0) cnt[tid] = 0u;
  const int bm = blockIdx.x * 128;
  const int bn = blockIdx.y * 128;
  const int lr = tid >> 2;          // 0..63  load row
  const int lc = (tid & 3) * 4;     // 0,4,8,12 (k within tile, float4)
  const int tm = (tid >> 4) * 8;    // 0..120
  const int tn = (tid & 15) * 8;

  float acc[8][8];
#pragma unroll
  for (int i = 0; i < 8; ++i)
#pragma unroll
    for (int j = 0; j < 8; ++j) acc[i][j] = 0.f;

  for (int k0 = 0; k0 < K; k0 += 16) {
    float4 a0 = *(const float4*)(A  + (size_t)(bm + lr)      * K + k0 + lc);
    float4 a1 = *(const float4*)(A  + (size_t)(bm + lr + 64) * K + k0 + lc);
    float4 b0 = *(const float4*)(Bm + (size_t)(bn + lr)      * K + k0 + lc);
    float4 b1 = *(const float4*)(Bm + (size_t)(bn + lr + 64) * K + k0 + lc);
    __syncthreads();   // previous iteration's LDS reads complete
    As[lc+0][lr]    = a0.x; As[lc+1][lr]    = a0.y; As[lc+2][lr]    = a0.z; As[lc+3][lr]    = a0.w;
    As[lc+0][lr+64] = a1.x; As[lc+1][lr+64] = a1.y; As[lc+2][lr+64] = a1.z; As[lc+3][lr+64] = a1.w;
    Bs[lc+0][lr]    = b0.x; Bs[lc+1][lr]    = b0.y; Bs[lc+2][lr]    = b0.z; Bs[lc+3][lr]    = b0.w;
    Bs[lc+0][lr+64] = b1.x; Bs[lc+1][lr+64] = b1.y; Bs[lc+2][lr+64] = b1.z; Bs[lc+3][lr+64] = b1.w;
    __syncthreads();
#pragma unroll
    for (int k = 0; k < 16; ++k) {
      float a[8], b[8];
      *(float4*)&a[0] = *(const float4*)&As[k][tm];
      *(float4*)&a[4] = *(const float4*)&As[k][tm + 4];
      *(float4*)&b[0] = *(const float4*)&Bs[k][tn];
      *(float4*)&b[4] = *(const float4*)&Bs[k][tn + 4];
#pragma unroll
      for (int i = 0; i < 8; ++i)
#pragma unroll
        for (int j = 0; j < 8; ++j) acc[i][j] += a[i] * b[j];
    }
  }

  float bv[8];
#pragma unroll
  for (int j = 0; j < 8; ++j) bv[j] = bias[bn + tn + j];
#pragma unroll
  for (int i = 0; i < 8; ++i) {
    float* crow = C + (size_t)(bm + tm + i) * N + bn + tn;
    float4 o0 = {acc[i][0]+bv[0], acc[i][1]+bv[1], acc[i][2]+bv[2], acc[i][3]+bv[3]};
    float4 o1 = {acc[i][4]+bv[4], acc[i][5]+bv[5], acc[i][6]+bv[6], acc[i][7]+bv[7]};
    *(float4*)(crow)     = o0;
    *(float4*)(crow + 4) = o1;
  }
}

// ---------------------------------------------------------------------------
// Fused recurrence: ALL 512 timesteps in one cooperative launch.
//   z[b][t][j] = tanh( pre(=z[b][t][j]) + sum_k h_prev[b][k]*W_hh[j][k] + b_hh[j] )
//
// Grid: 256 blocks x 256 threads, 1 block/CU (144 KB LDS).
//   bg = blockIdx&7  -> batch group b in [4bg, 4bg+4)
//   js = blockIdx>>3 -> output slice j in [32js, 32js+32)
// W_hh slice (32 rows x 1024 = 128 KB) lives in LDS for the whole kernel.
// Cross-block dependency exists ONLY among the 32 blocks sharing bg, so each
// bg-group has its own monotonic device-scope barrier counter (128 B apart).
// z rows are never overwritten (each t writes a distinct slice), so the only
// ordering needed is "step t-1 stores visible before step t h-reads".
// ---------------------------------------------------------------------------
__global__ __launch_bounds__(256)
void rnn_fused(float* __restrict__ z, const float* __restrict__ h0,
               const float* __restrict__ Whh, const float* __restrict__ bhh,
               unsigned* __restrict__ cnt) {
  __shared__ float Ws[32][1024];   // 128 KB: persistent W_hh slice
  __shared__ float hs[4][1024];    // 16 KB: h_{t-1} tile, restaged per step
  __shared__ float bs[32];         // b_hh slice

  const int tid = threadIdx.x;
  const int bg  = blockIdx.x & 7;
  const int js  = blockIdx.x >> 3;
  const int j0  = js * 32;
  const int b0  = bg * 4;
  unsigned* mycnt = cnt + bg * 32;   // 128 B apart: no cross-group contention

  // ---- one-time stage of W rows j0..j0+31 (contiguous 128 KB = 8192 float4) ----
  {
    const float4* src = (const float4*)(Whh + (size_t)j0 * H_);
    float4*       dst = (float4*)&Ws[0][0];
#pragma unroll 4
    for (int i = 0; i < 32; ++i) dst[tid + 256 * i] = src[tid + 256 * i];
  }
  if (tid < 32) bs[tid] = bhh[j0 + tid];

  const int srow = tid >> 6;        // 0..3   (h staging row)
  const int sc   = tid & 63;        // float4 col base
  const int jg   = tid >> 5;        // 0..7   (4-j group)
  const int ksl  = tid & 31;        // 32-way k split

  for (int t = 0; t < T_; ++t) {
    if (t) {
      __syncthreads();              // all lanes' step t-1 stores issued & drained
      if (tid == 0) {
        __hip_atomic_fetch_add(mycnt, 1u, __ATOMIC_RELEASE, __HIP_MEMORY_SCOPE_AGENT);
        const unsigned target = 32u * (unsigned)t;
        while (__hip_atomic_load(mycnt, __ATOMIC_RELAXED, __HIP_MEMORY_SCOPE_AGENT) < target)
          __builtin_amdgcn_s_sleep(1);
        __threadfence();            // acquire: invalidate stale caches before h reads
      }
    }
    __syncthreads();

    // ---- stage h_{t-1}[b0..b0+3][:] (16 KB, coalesced) ----
    {
      const float* hsrc = (t == 0)
          ? (h0 + (size_t)(b0 + srow) * H_)
          : (z + ((size_t)(b0 + srow) * T_ + (t - 1)) * H_);
      const float4* s4 = (const float4*)hsrc;
#pragma unroll
      for (int i = 0; i < 4; ++i)
        *(float4*)&hs[srow][(sc + 64 * i) * 4] = s4[sc + 64 * i];
    }
    __syncthreads();

    // ---- 4j x 4b microtile over this thread's 8 float4 k-chunks ----
    float acc[4][4];
#pragma unroll
    for (int jj = 0; jj < 4; ++jj)
#pragma unroll
      for (int bb = 0; bb < 4; ++bb) acc[jj][bb] = 0.f;

#pragma unroll
    for (int kc = 0; kc < 8; ++kc) {
      const int k = ksl * 4 + kc * 128;
      float4 ha = *(const float4*)&hs[0][k];
      float4 hb = *(const float4*)&hs[1][k];
      float4 hc = *(const float4*)&hs[2][k];
      float4 hd = *(const float4*)&hs[3][k];
#pragma unroll
      for (int jj = 0; jj < 4; ++jj) {
        float4 wv = *(const float4*)&Ws[jg * 4 + jj][k];
        acc[jj][0] += wv.x*ha.x + wv.y*ha.y + wv.z*ha.z + wv.w*ha.w;
        acc[jj][1] += wv.x*hb.x + wv.y*hb.y + wv.z*hb.z + wv.w*hb.w;
        acc[jj][2] += wv.x*hc.x + wv.y*hc.y + wv.z*hc.z + wv.w*hc.w;
        acc[jj][3] += wv.x*hd.x + wv.y*hd.y + wv.z*hd.z + wv.w*hd.w;
      }
    }

    // ---- butterfly reduce over the 32 k-split lanes (within wave halves) ----
#pragma unroll
    for (int off = 16; off; off >>= 1)
#pragma unroll
      for (int jj = 0; jj < 4; ++jj)
#pragma unroll
        for (int bb = 0; bb < 4; ++bb)
          acc[jj][bb] += __shfl_xor(acc[jj][bb], off, 64);

    // ---- lanes ksl<16 write the 16 (jj,bb) outputs of this jg ----
    if (ksl < 16) {
      float v = 0.f;
#pragma unroll
      for (int i = 0; i < 16; ++i) if (ksl == i) v = acc[i >> 2][i & 3];
      const int jj = ksl >> 2;
      const int bb = ksl & 3;
      const size_t idx = ((size_t)(b0 + bb) * T_ + t) * H_ + (j0 + jg * 4 + jj);
      z[idx] = tanhf(v + z[idx] + bs[jg * 4 + jj]);   // + pre + bias
    }
    // next iteration's pre-barrier __syncthreads covers hs reuse
  }
}

// ---------------------------------------------------------------------------
// Row softmax in place over O_=512 columns. One wave per row.
// ---------------------------------------------------------------------------
__global__ __launch_bounds__(256)
void softmax_rows(float* __restrict__ P) {
  const int row  = blockIdx.x * 4 + (threadIdx.x >> 6);
  const int lane = threadIdx.x & 63;
  float* p = P + (size_t)row * O_;
  float4 v0 = *(const float4*)(p + lane * 4);
  float4 v1 = *(const float4*)(p + 256 + lane * 4);

  float m = fmaxf(fmaxf(fmaxf(v0.x, v0.y), fmaxf(v0.z, v0.w)),
                  fmaxf(fmaxf(v1.x, v1.y), fmaxf(v1.z, v1.w)));
#pragma unroll
  for (int off = 32; off; off >>= 1) m = fmaxf(m, __shfl_xor(m, off, 64));

  v0.x = __expf(v0.x - m); v0.y = __expf(v0.y - m);
  v0.z = __expf(v0.z - m); v0.w = __expf(v0.w - m);
  v1.x = __expf(v1.x - m); v1.y = __expf(v1.y - m);
  v1.z = __expf(v1.z - m); v1.w = __expf(v1.w - m);

  float s = v0.x + v0.y + v0.z + v0.w + v1.x + v1.y + v1.z + v1.w;
#pragma unroll
  for (int off = 32; off; off >>= 1) s += __shfl_xor(s, off, 64);
  const float inv = 1.f / s;

  v0.x *= inv; v0.y *= inv; v0.z *= inv; v0.w *= inv;
  v1.x *= inv; v1.y *= inv; v1.z *= inv; v1.w *= inv;
  *(float4*)(p + lane * 4)       = v0;
  *(float4*)(p + 256 + lane * 4) = v1;
}

// ---------------------------------------------------------------------------
extern "C" void kernel_launch(void* const* d_in, const int* in_sizes, int n_in,
                              void* d_out, int out_size, void* d_ws, size_t ws_size,
                              hipStream_t stream) {
  const float* x    = (const float*)d_in[0];   // [B,T,I]
  const float* h0   = (const float*)d_in[1];   // [1,B,H]
  const float* Wih  = (const float*)d_in[2];   // [H,I]
  const float* Whh  = (const float*)d_in[3];   // [H,H]
  const float* bih  = (const float*)d_in[4];   // [H]
  const float* bhh  = (const float*)d_in[5];   // [H]
  const float* Wout = (const float*)d_in[6];   // [O,H]
  const float* bout = (const float*)d_in[7];   // [O]

  float* outp = (float*)d_out;                       // [B,T,O]
  float* z    = (float*)d_out + (size_t)MT * O_;     // [B,T,H]

  // Barrier counters live in a device global (d_ws may be zero-sized).
  static unsigned* cnt = nullptr;
  if (cnt == nullptr) {
    void* p = nullptr;
    hipGetSymbolAddress(&p, HIP_SYMBOL(g_cnt));
    cnt = (unsigned*)p;
  }

  // Phase 1: pre = x @ W_ih^T + b_ih, written directly into z region.
  // Block (0,0) also zeroes the barrier counters for the cooperative kernel.
  gemm_nt_bias<<<dim3(MT / 128, H_ / 128), 256, 0, stream>>>(z, x, Wih, bih, MT, H_, I_, cnt);

  // Phase 2: all 512 recurrence steps in ONE cooperative persistent kernel.
  {
    float* z_a = z; const float* h0_a = h0; const float* Whh_a = Whh;
    const float* bhh_a = bhh; unsigned* cnt_a = cnt;
    void* kargs[] = {&z_a, &h0_a, &Whh_a, &bhh_a, &cnt_a};
    hipLaunchCooperativeKernel((const void*)rnn_fused, dim3(256), dim3(256),
                               kargs, 0, stream);
  }

  // Phase 3: logits = z @ W_out^T + b_out, then row softmax in place
  gemm_nt_bias<<<dim3(MT / 128, O_ / 128), 256, 0, stream>>>(outp, z, Wout, bout, MT, O_, H_, nullptr);
  softmax_rows<<<dim3(MT / 4), 256, 0, stream>>>(outp);
}

// Round 3
// 2122.780 us; speedup vs baseline: 2.8830x; 2.8830x over previous
//
#include <hip/hip_runtime.h>
#include <math.h>

#define B_ 32
#define T_ 512
#define I_ 512
#define H_ 1024
#define O_ 512
#define MT (B_*T_)   // 16384 rows

// Barrier counters: 8 groups x 32 uints (128 B apart). Device global; zeroed
// by phase-1 GEMM block (0,0) so each graph replay starts clean.
__device__ unsigned g_cnt[256];

// ---------------------------------------------------------------------------
// GEMM: C[m][n] = bias[n] + sum_k A[m][k] * Bm[n][k]   (both row-major, "NT")
// ---------------------------------------------------------------------------
__global__ __launch_bounds__(256)
void gemm_nt_bias(float* __restrict__ C, const float* __restrict__ A,
                  const float* __restrict__ Bm, const float* __restrict__ bias,
                  int M, int N, int K, unsigned* __restrict__ cnt) {
  __shared__ float As[16][132];
  __shared__ float Bs[16][132];
  const int tid = threadIdx.x;
  if (cnt != nullptr && blockIdx.x == 0 && blockIdx.y == 0) cnt[tid] = 0u;
  const int bm = blockIdx.x * 128;
  const int bn = blockIdx.y * 128;
  const int lr = tid >> 2;
  const int lc = (tid & 3) * 4;
  const int tm = (tid >> 4) * 8;
  const int tn = (tid & 15) * 8;

  float acc[8][8];
#pragma unroll
  for (int i = 0; i < 8; ++i)
#pragma unroll
    for (int j = 0; j < 8; ++j) acc[i][j] = 0.f;

  for (int k0 = 0; k0 < K; k0 += 16) {
    float4 a0 = *(const float4*)(A  + (size_t)(bm + lr)      * K + k0 + lc);
    float4 a1 = *(const float4*)(A  + (size_t)(bm + lr + 64) * K + k0 + lc);
    float4 b0 = *(const float4*)(Bm + (size_t)(bn + lr)      * K + k0 + lc);
    float4 b1 = *(const float4*)(Bm + (size_t)(bn + lr + 64) * K + k0 + lc);
    __syncthreads();
    As[lc+0][lr]    = a0.x; As[lc+1][lr]    = a0.y; As[lc+2][lr]    = a0.z; As[lc+3][lr]    = a0.w;
    As[lc+0][lr+64] = a1.x; As[lc+1][lr+64] = a1.y; As[lc+2][lr+64] = a1.z; As[lc+3][lr+64] = a1.w;
    Bs[lc+0][lr]    = b0.x; Bs[lc+1][lr]    = b0.y; Bs[lc+2][lr]    = b0.z; Bs[lc+3][lr]    = b0.w;
    Bs[lc+0][lr+64] = b1.x; Bs[lc+1][lr+64] = b1.y; Bs[lc+2][lr+64] = b1.z; Bs[lc+3][lr+64] = b1.w;
    __syncthreads();
#pragma unroll
    for (int k = 0; k < 16; ++k) {
      float a[8], b[8];
      *(float4*)&a[0] = *(const float4*)&As[k][tm];
      *(float4*)&a[4] = *(const float4*)&As[k][tm + 4];
      *(float4*)&b[0] = *(const float4*)&Bs[k][tn];
      *(float4*)&b[4] = *(const float4*)&Bs[k][tn + 4];
#pragma unroll
      for (int i = 0; i < 8; ++i)
#pragma unroll
        for (int j = 0; j < 8; ++j) acc[i][j] += a[i] * b[j];
    }
  }

  float bv[8];
#pragma unroll
  for (int j = 0; j < 8; ++j) bv[j] = bias[bn + tn + j];
#pragma unroll
  for (int i = 0; i < 8; ++i) {
    float* crow = C + (size_t)(bm + tm + i) * N + bn + tn;
    float4 o0 = {acc[i][0]+bv[0], acc[i][1]+bv[1], acc[i][2]+bv[2], acc[i][3]+bv[3]};
    float4 o1 = {acc[i][4]+bv[4], acc[i][5]+bv[5], acc[i][6]+bv[6], acc[i][7]+bv[7]};
    *(float4*)(crow)     = o0;
    *(float4*)(crow + 4) = o1;
  }
}

// ---------------------------------------------------------------------------
// Fused recurrence, all 512 steps, one cooperative launch.
// Key change vs prev round: cross-XCD h exchange goes through MALL/L3 via
// sc0 sc1 (L1+L2-bypass) loads/stores, so NO buffer_wbl2 / buffer_inv (full
// L2 flush+invalidate) is needed per step. Counter atomics are RELAXED agent
// scope (no fence codegen). Only s_waitcnt vmcnt(0) + s_barrier remain.
//
// Grid 256x512: block (bg=blk&7, js=blk>>3) owns batches [4bg,4bg+4) x
// output cols [32js,32js+32). Per-thread: jg=tid>>6 (4-j group),
// ksl=tid&63 (64-way k split). W slice lives in 64 VGPRs (constant over t).
// ---------------------------------------------------------------------------
__global__ __launch_bounds__(512, 2)
void rnn_fused(float* __restrict__ z, const float* __restrict__ h0,
               const float* __restrict__ Whh, const float* __restrict__ bhh,
               unsigned* __restrict__ cnt) {
  __shared__ float hs[4][1024];    // 16 KB: h_{t-1} tile

  const int tid = threadIdx.x;
  const int bg  = blockIdx.x & 7;
  const int js  = blockIdx.x >> 3;
  const int j0  = js * 32;
  const int b0  = bg * 4;
  unsigned* mycnt = cnt + bg * 32;

  const int jg   = tid >> 6;       // 0..7
  const int ksl  = tid & 63;       // 64-way k split
  const int w    = ksl >> 2;       // output idx this lane holds post-reduce
  const int jj   = w >> 2;         // 0..3
  const int bb   = w & 3;          // 0..3
  const int srow = tid >> 7;       // 0..3 staging row
  const int sc   = tid & 127;      // staging float4 col

  // ---- W slice into registers (constant across all 512 steps) ----
  float4 wr[4][4];                 // [kc][jj] : W[j0+jg*4+jj][ksl*4+kc*256 ..+4]
#pragma unroll
  for (int kc = 0; kc < 4; ++kc)
#pragma unroll
    for (int j = 0; j < 4; ++j)
      wr[kc][j] = *(const float4*)(Whh + (size_t)(j0 + jg*4 + j) * H_ + ksl*4 + kc*256);

  const float breg = bhh[j0 + jg*4 + jj];

  for (int t = 0; t < T_; ++t) {
    if (t) {
      __syncthreads();             // all waves' step t-1 stores drained (vmcnt 0)
      if (tid == 0) {
        __hip_atomic_fetch_add(mycnt, 1u, __ATOMIC_RELAXED, __HIP_MEMORY_SCOPE_AGENT);
        const unsigned target = 32u * (unsigned)t;
        while (__hip_atomic_load(mycnt, __ATOMIC_RELAXED, __HIP_MEMORY_SCOPE_AGENT) < target)
          __builtin_amdgcn_s_sleep(1);
      }
      __syncthreads();
    }

    // ---- issue pre-load + h staging loads (L1/L2-bypass), one waitcnt ----
    const float* zpre = z + ((size_t)(b0 + bb) * T_ + t) * H_ + j0 + jg*4 + jj;
    const float* hrow = (t == 0)
        ? (h0 + (size_t)(b0 + srow) * H_ + sc * 4)
        : (z + ((size_t)(b0 + srow) * T_ + (t - 1)) * H_ + sc * 4);
    float pre; float4 ha, hb;
    asm volatile(
      "global_load_dword %0, %3, off sc0 sc1\n\t"
      "global_load_dwordx4 %1, %4, off sc0 sc1\n\t"
      "global_load_dwordx4 %2, %4, off offset:2048 sc0 sc1\n\t"
      "s_waitcnt vmcnt(0)"
      : "=&v"(pre), "=&v"(ha), "=&v"(hb)
      : "v"(zpre), "v"(hrow)
      : "memory");
    *(float4*)&hs[srow][sc * 4]       = ha;
    *(float4*)&hs[srow][sc * 4 + 512] = hb;
    __syncthreads();

    // ---- 4j x 4b microtile over this lane's 4 float4 k-chunks ----
    float acc[16];
#pragma unroll
    for (int m = 0; m < 16; ++m) acc[m] = 0.f;
#pragma unroll
    for (int kc = 0; kc < 4; ++kc) {
      const int k = ksl * 4 + kc * 256;
      float4 h0v = *(const float4*)&hs[0][k];
      float4 h1v = *(const float4*)&hs[1][k];
      float4 h2v = *(const float4*)&hs[2][k];
      float4 h3v = *(const float4*)&hs[3][k];
#pragma unroll
      for (int j = 0; j < 4; ++j) {
        float4 wv = wr[kc][j];
        acc[j*4+0] += wv.x*h0v.x + wv.y*h0v.y + wv.z*h0v.z + wv.w*h0v.w;
        acc[j*4+1] += wv.x*h1v.x + wv.y*h1v.y + wv.z*h1v.z + wv.w*h1v.w;
        acc[j*4+2] += wv.x*h2v.x + wv.y*h2v.y + wv.z*h2v.z + wv.w*h2v.w;
        acc[j*4+3] += wv.x*h3v.x + wv.y*h3v.y + wv.z*h3v.z + wv.w*h3v.w;
      }
    }

    // ---- packing reduction over 64 lanes: 17 shuffles, value w -> lane 4w ----
    const bool b5 = (ksl & 32) != 0;
    float r8[8];
#pragma unroll
    for (int m = 0; m < 8; ++m) {
      float keep = b5 ? acc[m+8] : acc[m];
      float send = b5 ? acc[m]   : acc[m+8];
      r8[m] = keep + __shfl_xor(send, 32, 64);
    }
    const bool b4 = (ksl & 16) != 0;
    float r4[4];
#pragma unroll
    for (int m = 0; m < 4; ++m) {
      float keep = b4 ? r8[m+4] : r8[m];
      float send = b4 ? r8[m]   : r8[m+4];
      r4[m] = keep + __shfl_xor(send, 16, 64);
    }
    const bool b3 = (ksl & 8) != 0;
    float r2[2];
#pragma unroll
    for (int m = 0; m < 2; ++m) {
      float keep = b3 ? r4[m+2] : r4[m];
      float send = b3 ? r4[m]   : r4[m+2];
      r2[m] = keep + __shfl_xor(send, 8, 64);
    }
    const bool b2 = (ksl & 4) != 0;
    float r1 = (b2 ? r2[1] : r2[0]) + __shfl_xor(b2 ? r2[0] : r2[1], 4, 64);
    r1 += __shfl_xor(r1, 2, 64);
    r1 += __shfl_xor(r1, 1, 64);
    // lane 4w now holds the full k-sum of output w = jj*4+bb

    if ((ksl & 3) == 0) {
      float v = tanhf(r1 + pre + breg);
      asm volatile("global_store_dword %0, %1, off sc0 sc1"
                   :: "v"(zpre), "v"(v) : "memory");
    }
    asm volatile("s_waitcnt vmcnt(0)" ::: "memory");
  }
}

// ---------------------------------------------------------------------------
// Row softmax in place over O_=512 columns. One wave per row.
// ---------------------------------------------------------------------------
__global__ __launch_bounds__(256)
void softmax_rows(float* __restrict__ P) {
  const int row  = blockIdx.x * 4 + (threadIdx.x >> 6);
  const int lane = threadIdx.x & 63;
  float* p = P + (size_t)row * O_;
  float4 v0 = *(const float4*)(p + lane * 4);
  float4 v1 = *(const float4*)(p + 256 + lane * 4);

  float m = fmaxf(fmaxf(fmaxf(v0.x, v0.y), fmaxf(v0.z, v0.w)),
                  fmaxf(fmaxf(v1.x, v1.y), fmaxf(v1.z, v1.w)));
#pragma unroll
  for (int off = 32; off; off >>= 1) m = fmaxf(m, __shfl_xor(m, off, 64));

  v0.x = __expf(v0.x - m); v0.y = __expf(v0.y - m);
  v0.z = __expf(v0.z - m); v0.w = __expf(v0.w - m);
  v1.x = __expf(v1.x - m); v1.y = __expf(v1.y - m);
  v1.z = __expf(v1.z - m); v1.w = __expf(v1.w - m);

  float s = v0.x + v0.y + v0.z + v0.w + v1.x + v1.y + v1.z + v1.w;
#pragma unroll
  for (int off = 32; off; off >>= 1) s += __shfl_xor(s, off, 64);
  const float inv = 1.f / s;

  v0.x *= inv; v0.y *= inv; v0.z *= inv; v0.w *= inv;
  v1.x *= inv; v1.y *= inv; v1.z *= inv; v1.w *= inv;
  *(float4*)(p + lane * 4)       = v0;
  *(float4*)(p + 256 + lane * 4) = v1;
}

// ---------------------------------------------------------------------------
extern "C" void kernel_launch(void* const* d_in, const int* in_sizes, int n_in,
                              void* d_out, int out_size, void* d_ws, size_t ws_size,
                              hipStream_t stream) {
  const float* x    = (const float*)d_in[0];   // [B,T,I]
  const float* h0   = (const float*)d_in[1];   // [1,B,H]
  const float* Wih  = (const float*)d_in[2];   // [H,I]
  const float* Whh  = (const float*)d_in[3];   // [H,H]
  const float* bih  = (const float*)d_in[4];   // [H]
  const float* bhh  = (const float*)d_in[5];   // [H]
  const float* Wout = (const float*)d_in[6];   // [O,H]
  const float* bout = (const float*)d_in[7];   // [O]

  float* outp = (float*)d_out;                       // [B,T,O]
  float* z    = (float*)d_out + (size_t)MT * O_;     // [B,T,H]

  static unsigned* cnt = nullptr;
  if (cnt == nullptr) {
    void* p = nullptr;
    hipGetSymbolAddress(&p, HIP_SYMBOL(g_cnt));
    cnt = (unsigned*)p;
  }

  // Phase 1: pre = x @ W_ih^T + b_ih, into z region; zeroes barrier counters.
  gemm_nt_bias<<<dim3(MT / 128, H_ / 128), 256, 0, stream>>>(z, x, Wih, bih, MT, H_, I_, cnt);

  // Phase 2: all 512 recurrence steps in one cooperative persistent kernel.
  {
    float* z_a = z; const float* h0_a = h0; const float* Whh_a = Whh;
    const float* bhh_a = bhh; unsigned* cnt_a = cnt;
    void* kargs[] = {&z_a, &h0_a, &Whh_a, &bhh_a, &cnt_a};
    hipLaunchCooperativeKernel((const void*)rnn_fused, dim3(256), dim3(512),
                               kargs, 0, stream);
  }

  // Phase 3: logits = z @ W_out^T + b_out, then row softmax in place
  gemm_nt_bias<<<dim3(MT / 128, O_ / 128), 256, 0, stream>>>(outp, z, Wout, bout, MT, O_, H_, nullptr);
  softmax_rows<<<dim3(MT / 4), 256, 0, stream>>>(outp);
}